// Round 8
// baseline (563.894 us; speedup 1.0000x reference)
//
#include <hip/hip_runtime.h>

#define NODES 100000
#define INDIM 256
#define HDIM 128
#define ODIM 40
#define NPX 12500   // nodes per XCD range (100000/8)

typedef short bf16x8 __attribute__((ext_vector_type(8)));   // 8 bf16 (4 VGPR)
typedef float f32x16 __attribute__((ext_vector_type(16)));  // MFMA 32x32 accumulator

// ---------------- CSR build (XCD-range partitioned, rows padded to %8) ----------------
// Padding entries index the dummy zero row (NODES) so agg loops have no tails and
// index loads vectorize to int4.

__global__ __launch_bounds__(256) void k_hist(const int* __restrict__ dst, int E,
                                              int* __restrict__ counts){
    int xcd = blockIdx.x & 7;
    int g   = blockIdx.x >> 3;            // 0..255
    int lo = xcd * NPX, hi = lo + NPX;
    for(int e = g * 256 + threadIdx.x; e < E; e += 65536){
        int d = dst[e];
        if(d >= lo && d < hi) atomicAdd(&counts[d], 1);
    }
}

__global__ __launch_bounds__(256) void k_fill(const int* __restrict__ src, const int* __restrict__ dst,
                                              int E, int* __restrict__ cursor, int* __restrict__ esrc){
    int xcd = blockIdx.x & 7;
    int g   = blockIdx.x >> 3;
    int lo = xcd * NPX, hi = lo + NPX;
    for(int e = g * 256 + threadIdx.x; e < E; e += 65536){
        int d = dst[e];
        if(d >= lo && d < hi){
            int p = atomicAdd(&cursor[d], 1);
            esrc[p] = src[e];
        }
    }
}

// per-chunk partial sums of PADDED counts
__global__ void k_psum(const int* __restrict__ counts, int* __restrict__ partial, int n){
    __shared__ int sm[256];
    int chunk = (n + 255) >> 8;
    int start = blockIdx.x * chunk;
    int end = min(start + chunk, n);
    int s = 0;
    for(int i = start + threadIdx.x; i < end; i += 256) s += (counts[i] + 7) & ~7;
    sm[threadIdx.x] = s;
    __syncthreads();
    for(int off = 128; off > 0; off >>= 1){
        if(threadIdx.x < off) sm[threadIdx.x] += sm[threadIdx.x + off];
        __syncthreads();
    }
    if(threadIdx.x == 0) partial[blockIdx.x] = sm[0];
}

__global__ void k_scan256(const int* __restrict__ partial, int* __restrict__ pscan){
    __shared__ int sm[256];
    int t = threadIdx.x;
    sm[t] = partial[t];
    __syncthreads();
    for(int off = 1; off < 256; off <<= 1){
        int v = (t >= off) ? sm[t - off] : 0;
        __syncthreads();
        sm[t] += v;
        __syncthreads();
    }
    pscan[t] = (t == 0) ? 0 : sm[t - 1];
}

// finalize padded row_start / cursor / dinv (dinv from TRUE count)
__global__ void k_scan_final(const int* __restrict__ counts, const int* __restrict__ pscan,
                             int n, int* __restrict__ row_start, int* __restrict__ cursor,
                             float* __restrict__ dinv){
    __shared__ int sm[512];
    int chunk = (n + 255) >> 8;
    int b = blockIdx.x, t = threadIdx.x;
    int idx = b * chunk + t;
    int c = (t < chunk && idx < n) ? counts[idx] : 0;
    int cp = (c + 7) & ~7;
    sm[t] = cp;
    __syncthreads();
    for(int off = 1; off < 512; off <<= 1){
        int v = (t >= off) ? sm[t - off] : 0;
        __syncthreads();
        sm[t] += v;
        __syncthreads();
    }
    if(t < chunk && idx < n){
        int rs = pscan[b] + sm[t] - cp;   // exclusive, padded
        row_start[idx] = rs;
        cursor[idx] = rs;
        dinv[idx] = rsqrtf((float)(c + 1));   // +1 self loop
        if(idx == n - 1) row_start[n] = rs + cp;
    }
}

// fill padding gap [cursor_final, row_start[i+1]) with dummy index n
__global__ void k_pad(const int* __restrict__ cursor, const int* __restrict__ row_start,
                      int* __restrict__ esrc, int n){
    int i = blockIdx.x * 256 + threadIdx.x;
    if(i >= n) return;
    int p = cursor[i], p1 = row_start[i + 1];
    for(; p < p1; ++p) esrc[p] = n;
}

// ---------------- W1 split/transpose into MFMA-fragment order ----------------
__global__ void k_wsplit(const float* __restrict__ W, unsigned short* __restrict__ whi,
                         unsigned short* __restrict__ wlo){
    int t = blockIdx.x * 256 + threadIdx.x;      // 4096 threads = (cf,kk,lane)
    int lane = t & 63;
    int kk = (t >> 6) & 15;
    int cf = t >> 10;
    int col = cf * 32 + (lane & 31);
    int kbase = kk * 16 + (lane >> 5) * 8;
    #pragma unroll
    for(int i = 0; i < 8; ++i){
        float f = W[(size_t)(kbase + i) * HDIM + col];
        unsigned u = __float_as_uint(f);
        unsigned short hs = (unsigned short)(u >> 16);
        float lf = f - __uint_as_float(u & 0xffff0000u);
        unsigned short ls = (unsigned short)(__float_as_uint(lf) >> 16);
        whi[(size_t)t * 8 + i] = hs;
        wlo[(size_t)t * 8 + i] = ls;
    }
}

// ---------------- GEMM1 (MFMA split-bf16): h' = dinv .* (x @ W1) ----------------
__device__ inline void split8(const float4 v0, const float4 v1, bf16x8& hi, bf16x8& lo){
    const float f[8] = {v0.x, v0.y, v0.z, v0.w, v1.x, v1.y, v1.z, v1.w};
    #pragma unroll
    for(int i = 0; i < 8; ++i){
        unsigned u = __float_as_uint(f[i]);
        hi[i] = (short)(u >> 16);
        float lf = f[i] - __uint_as_float(u & 0xffff0000u);
        lo[i] = (short)(__float_as_uint(lf) >> 16);
    }
}

__global__ __launch_bounds__(256, 3) void k_gemm1(const float* __restrict__ x,
        const bf16x8* __restrict__ whi, const bf16x8* __restrict__ wlo,
        const float* __restrict__ dinv, float* __restrict__ h, int n){
    int wid = blockIdx.x * 4 + (threadIdx.x >> 6);
    if(wid >= (n >> 5)) return;              // 3125 waves exactly (100000 = 32*3125)
    int lane = threadIdx.x & 63;
    int r  = lane & 31;
    int hk = lane >> 5;
    int row0 = wid * 32;

    f32x16 acc[4];
    #pragma unroll
    for(int cf = 0; cf < 4; ++cf)
        #pragma unroll
        for(int i = 0; i < 16; ++i) acc[cf][i] = 0.f;

    const float* ap = x + (size_t)(row0 + r) * INDIM + hk * 8;

    for(int kk = 0; kk < 16; ++kk){          // K = 256, BK = 16
        int ko = kk * 16;
        float4 a0 = *(const float4*)(ap + ko);
        float4 a1 = *(const float4*)(ap + ko + 4);
        bf16x8 bh[4], bl[4];
        #pragma unroll
        for(int cf = 0; cf < 4; ++cf){
            bh[cf] = whi[(cf * 16 + kk) * 64 + lane];
            bl[cf] = wlo[(cf * 16 + kk) * 64 + lane];
        }
        bf16x8 ah, al;
        split8(a0, a1, ah, al);
        #pragma unroll
        for(int cf = 0; cf < 4; ++cf){
            acc[cf] = __builtin_amdgcn_mfma_f32_32x32x16_bf16(ah, bh[cf], acc[cf], 0, 0, 0);
            acc[cf] = __builtin_amdgcn_mfma_f32_32x32x16_bf16(ah, bl[cf], acc[cf], 0, 0, 0);
            acc[cf] = __builtin_amdgcn_mfma_f32_32x32x16_bf16(al, bh[cf], acc[cf], 0, 0, 0);
        }
    }

    #pragma unroll
    for(int reg = 0; reg < 16; ++reg){
        int row = row0 + (reg & 3) + 8 * (reg >> 2) + 4 * hk;
        float di = dinv[row];
        float* hp = h + (size_t)row * HDIM + r;
        #pragma unroll
        for(int cf = 0; cf < 4; ++cf)
            hp[cf * 32] = acc[cf][reg] * di;
    }
}

// ---------------- GEMM2: h' = dinv .* (a @ W2), [N,128]@[128,40] ----------------
__global__ __launch_bounds__(256) void k_gemm2(const float* __restrict__ a, const float* __restrict__ W,
                                               const float* __restrict__ dinv,
                                               float* __restrict__ h, int n){
    __shared__ float xs[64][132];
    __shared__ float ws[HDIM][ODIM];
    int tid = threadIdx.x;
    int row0 = blockIdx.x * 64;
    #pragma unroll
    for(int jj = 0; jj < 8; ++jj){
        int f = tid + 256 * jj;       // float4 index, 2048 total
        int r = f >> 5;
        int c4 = (f & 31) << 2;
        float4 v = make_float4(0.f, 0.f, 0.f, 0.f);
        int grow = row0 + r;
        if(grow < n) v = *(const float4*)&a[(size_t)grow * HDIM + c4];
        *(float4*)&xs[r][c4] = v;
    }
    #pragma unroll
    for(int jj = 0; jj < 5; ++jj){
        int f = tid + 256 * jj;       // 1280 float4 exact
        int r = f / 10;
        int c4 = (f % 10) << 2;
        *(float4*)&ws[r][c4] = *(const float4*)&W[(size_t)r * ODIM + c4];
    }
    __syncthreads();
    int q = tid & 3, r = tid >> 2;
    float acc[10];
    #pragma unroll
    for(int j = 0; j < 10; ++j) acc[j] = 0.f;
    #pragma unroll 4
    for(int k = 0; k < HDIM; ++k){
        float xv = xs[r][k];
        #pragma unroll
        for(int j = 0; j < 5; ++j){
            float2 w = *(const float2*)&ws[k][2 * q + 8 * j];
            acc[2*j+0] += xv * w.x;
            acc[2*j+1] += xv * w.y;
        }
    }
    int grow = row0 + r;
    if(grow < n){
        float dv = dinv[grow];
        #pragma unroll
        for(int j = 0; j < 5; ++j){
            float2 o; o.x = acc[2*j] * dv; o.y = acc[2*j+1] * dv;
            *(float2*)&h[(size_t)grow * ODIM + 2 * q + 8 * j] = o;
        }
    }
}

// ---------------- Aggregation (gather over padded CSR, rows pre-scaled by dinv[src]) ----------------
// agg1: 2 nodes/wave, float4/lane (512B row per VMEM). Rows %8 with dummy-row padding:
// int4 index loads, 16 gathers in flight, zero tail code.
__global__ __launch_bounds__(256) void k_agg1(const float4* __restrict__ h4, const int* __restrict__ row_start,
                                              const int* __restrict__ esrc, const float* __restrict__ dinv,
                                              const float4* __restrict__ bias4, float4* __restrict__ out4, int n){
    int wav = (blockIdx.x * 256 + threadIdx.x) >> 6;
    int lane = threadIdx.x & 63;
    int half = lane >> 5;
    int node = wav * 2 + half;
    if(node >= n) return;
    int r32 = lane & 31;                     // float4 column 0..31 (128 feats)

    float4 acc = h4[(size_t)node * 32 + r32];    // self loop: h'[i]
    int e = row_start[node], e1 = row_start[node + 1];

    for(; e + 16 <= e1; e += 16){
        int4 sa = *(const int4*)&esrc[e];
        int4 sb = *(const int4*)&esrc[e + 4];
        int4 sc = *(const int4*)&esrc[e + 8];
        int4 sd = *(const int4*)&esrc[e + 12];
        float4 m0  = h4[(size_t)sa.x * 32 + r32];
        float4 m1  = h4[(size_t)sa.y * 32 + r32];
        float4 m2  = h4[(size_t)sa.z * 32 + r32];
        float4 m3  = h4[(size_t)sa.w * 32 + r32];
        float4 m4  = h4[(size_t)sb.x * 32 + r32];
        float4 m5  = h4[(size_t)sb.y * 32 + r32];
        float4 m6  = h4[(size_t)sb.z * 32 + r32];
        float4 m7  = h4[(size_t)sb.w * 32 + r32];
        float4 m8  = h4[(size_t)sc.x * 32 + r32];
        float4 m9  = h4[(size_t)sc.y * 32 + r32];
        float4 m10 = h4[(size_t)sc.z * 32 + r32];
        float4 m11 = h4[(size_t)sc.w * 32 + r32];
        float4 m12 = h4[(size_t)sd.x * 32 + r32];
        float4 m13 = h4[(size_t)sd.y * 32 + r32];
        float4 m14 = h4[(size_t)sd.z * 32 + r32];
        float4 m15 = h4[(size_t)sd.w * 32 + r32];
        acc.x += ((m0.x + m1.x) + (m2.x + m3.x)) + ((m4.x + m5.x) + (m6.x + m7.x))
               + ((m8.x + m9.x) + (m10.x + m11.x)) + ((m12.x + m13.x) + (m14.x + m15.x));
        acc.y += ((m0.y + m1.y) + (m2.y + m3.y)) + ((m4.y + m5.y) + (m6.y + m7.y))
               + ((m8.y + m9.y) + (m10.y + m11.y)) + ((m12.y + m13.y) + (m14.y + m15.y));
        acc.z += ((m0.z + m1.z) + (m2.z + m3.z)) + ((m4.z + m5.z) + (m6.z + m7.z))
               + ((m8.z + m9.z) + (m10.z + m11.z)) + ((m12.z + m13.z) + (m14.z + m15.z));
        acc.w += ((m0.w + m1.w) + (m2.w + m3.w)) + ((m4.w + m5.w) + (m6.w + m7.w))
               + ((m8.w + m9.w) + (m10.w + m11.w)) + ((m12.w + m13.w) + (m14.w + m15.w));
    }
    if(e < e1){                               // exactly 8 remain (rows are %8)
        int4 sa = *(const int4*)&esrc[e];
        int4 sb = *(const int4*)&esrc[e + 4];
        float4 m0 = h4[(size_t)sa.x * 32 + r32];
        float4 m1 = h4[(size_t)sa.y * 32 + r32];
        float4 m2 = h4[(size_t)sa.z * 32 + r32];
        float4 m3 = h4[(size_t)sa.w * 32 + r32];
        float4 m4 = h4[(size_t)sb.x * 32 + r32];
        float4 m5 = h4[(size_t)sb.y * 32 + r32];
        float4 m6 = h4[(size_t)sb.z * 32 + r32];
        float4 m7 = h4[(size_t)sb.w * 32 + r32];
        acc.x += ((m0.x + m1.x) + (m2.x + m3.x)) + ((m4.x + m5.x) + (m6.x + m7.x));
        acc.y += ((m0.y + m1.y) + (m2.y + m3.y)) + ((m4.y + m5.y) + (m6.y + m7.y));
        acc.z += ((m0.z + m1.z) + (m2.z + m3.z)) + ((m4.z + m5.z) + (m6.z + m7.z));
        acc.w += ((m0.w + m1.w) + (m2.w + m3.w)) + ((m4.w + m5.w) + (m6.w + m7.w));
    }

    float di = dinv[node];
    float4 b = bias4[r32];
    float4 o;
    o.x = fmaxf(fmaf(acc.x, di, b.x), 0.f);
    o.y = fmaxf(fmaf(acc.y, di, b.y), 0.f);
    o.z = fmaxf(fmaf(acc.z, di, b.z), 0.f);
    o.w = fmaxf(fmaf(acc.w, di, b.w), 0.f);
    out4[(size_t)node * 32 + r32] = o;
}

// agg2: dim 40, one wave/node (lanes 0..39), padded rows, int4 idx, 8-deep
__global__ __launch_bounds__(256) void k_agg2(const float* __restrict__ h, const int* __restrict__ row_start,
                                              const int* __restrict__ esrc, const float* __restrict__ dinv,
                                              const float* __restrict__ bias, float* __restrict__ out, int n){
    int wid = (blockIdx.x * 256 + threadIdx.x) >> 6;
    int lane = threadIdx.x & 63;
    if(wid >= n || lane >= ODIM) return;
    float a = h[(size_t)wid * ODIM + lane];        // self loop: h'[i]
    int e = row_start[wid], e1 = row_start[wid + 1];
    for(; e < e1; e += 8){
        int4 sa = *(const int4*)&esrc[e];
        int4 sb = *(const int4*)&esrc[e + 4];
        float m0 = h[(size_t)sa.x * ODIM + lane];
        float m1 = h[(size_t)sa.y * ODIM + lane];
        float m2 = h[(size_t)sa.z * ODIM + lane];
        float m3 = h[(size_t)sa.w * ODIM + lane];
        float m4 = h[(size_t)sb.x * ODIM + lane];
        float m5 = h[(size_t)sb.y * ODIM + lane];
        float m6 = h[(size_t)sb.z * ODIM + lane];
        float m7 = h[(size_t)sb.w * ODIM + lane];
        a += ((m0 + m1) + (m2 + m3)) + ((m4 + m5) + (m6 + m7));
    }
    out[(size_t)wid * ODIM + lane] = fmaf(a, dinv[wid], bias[lane]);
}

extern "C" void kernel_launch(void* const* d_in, const int* in_sizes, int n_in,
                              void* d_out, int out_size, void* d_ws, size_t ws_size,
                              hipStream_t stream){
    const float* x  = (const float*)d_in[0];
    const int*   ei = (const int*)d_in[1];   // [2][E] int32
    const float* W1 = (const float*)d_in[2];
    const float* b1 = (const float*)d_in[3];
    const float* W2 = (const float*)d_in[4];
    const float* b2 = (const float*)d_in[5];
    float* out = (float*)d_out;

    const int n = NODES;
    const int E = in_sizes[1] / 2;
    const int* esrc_in = ei;
    const int* edst_in = ei + E;

    char* w = (char*)d_ws;
    int*   counts    = (int*)(w);                        // 400 KB
    int*   row_start = (int*)(w + (1u << 19));           // 400 KB (+1)
    int*   cursor    = (int*)(w + (2u << 19));           // 400 KB
    int*   partial   = (int*)(w + (3u << 19));           // 1 KB
    int*   pscan     = (int*)(w + (3u << 19) + 4096);    // 1 KB
    float* dinv      = (float*)(w + (4u << 19));         // 400 KB
    unsigned short* whi = (unsigned short*)(w + (6u << 19));   // 64 KB  W1 frag hi
    unsigned short* wlo = (unsigned short*)(w + (7u << 19));   // 64 KB  W1 frag lo
    int*   esrc      = (int*)(w + (4u << 20));           // padded: <=9.6 MB (4..13.6 MB)
    float* h1        = (float*)(w + (16u << 20));        // [N+1][128] = 51.2 MB + 512B
    float* h1r       = (float*)(w + (68u << 20));        // [N][128] = 51.2 MB
    float* h2        = h1;                                // reuse (h1 dead after agg1), [N+1][40]

    hipMemsetAsync(counts, 0, n * sizeof(int), stream);
    k_hist<<<2048, 256, 0, stream>>>(edst_in, E, counts);
    k_psum<<<256, 256, 0, stream>>>(counts, partial, n);
    k_scan256<<<1, 256, 0, stream>>>(partial, pscan);
    k_scan_final<<<256, 512, 0, stream>>>(counts, pscan, n, row_start, cursor, dinv);
    k_fill<<<2048, 256, 0, stream>>>(esrc_in, edst_in, E, cursor, esrc);
    k_pad<<<(n + 255) / 256, 256, 0, stream>>>(cursor, row_start, esrc, n);
    k_wsplit<<<16, 256, 0, stream>>>(W1, whi, wlo);

    k_gemm1<<<(NODES / 32 + 3) / 4, 256, 0, stream>>>(x, (const bf16x8*)whi, (const bf16x8*)wlo,
                                                      dinv, h1, n);
    // dummy zero row for agg1 gathers (index n)
    hipMemsetAsync(h1 + (size_t)n * HDIM, 0, HDIM * sizeof(float), stream);
    k_agg1<<<(n / 2 + 3) / 4, 256, 0, stream>>>((const float4*)h1, row_start, esrc, dinv,
                                                (const float4*)b1, (float4*)h1r, n);
    k_gemm2<<<(n + 63) / 64, 256, 0, stream>>>(h1r, W2, dinv, h2, n);
    // dummy zero row for agg2 gathers (h1 region is dead now; row n of h2 layout)
    hipMemsetAsync(h2 + (size_t)n * ODIM, 0, ODIM * sizeof(float), stream);
    k_agg2<<<(n * 64 + 255) / 256, 256, 0, stream>>>(h2, row_start, esrc, dinv, b2, out, n);
}

// Round 11
// 495.677 us; speedup vs baseline: 1.1376x; 1.1376x over previous
//
#include <hip/hip_runtime.h>

#define NODES 100000
#define INDIM 256
#define HDIM 128
#define ODIM 40
#define NPX 12500   // nodes per XCD range (100000/8)

typedef short bf16x8 __attribute__((ext_vector_type(8)));   // 8 bf16 (4 VGPR)
typedef float f32x16 __attribute__((ext_vector_type(16)));  // MFMA 32x32 accumulator

__device__ inline unsigned short f2bf(float f){   // RNE float->bf16
    unsigned u = __float_as_uint(f);
    return (unsigned short)((u + 0x7fffu + ((u >> 16) & 1u)) >> 16);
}

// ---------------- CSR build (XCD-range partitioned, rows padded to %8) ----------------

__global__ __launch_bounds__(256) void k_hist(const int* __restrict__ dst, int E,
                                              int* __restrict__ counts){
    int xcd = blockIdx.x & 7;
    int g   = blockIdx.x >> 3;            // 0..255
    int lo = xcd * NPX, hi = lo + NPX;
    for(int e = g * 256 + threadIdx.x; e < E; e += 65536){
        int d = dst[e];
        if(d >= lo && d < hi) atomicAdd(&counts[d], 1);
    }
}

__global__ __launch_bounds__(256) void k_fill(const int* __restrict__ src, const int* __restrict__ dst,
                                              int E, int* __restrict__ cursor, int* __restrict__ esrc){
    int xcd = blockIdx.x & 7;
    int g   = blockIdx.x >> 3;
    int lo = xcd * NPX, hi = lo + NPX;
    for(int e = g * 256 + threadIdx.x; e < E; e += 65536){
        int d = dst[e];
        if(d >= lo && d < hi){
            int p = atomicAdd(&cursor[d], 1);
            esrc[p] = src[e];
        }
    }
}

// per-chunk partial sums of PADDED counts
__global__ void k_psum(const int* __restrict__ counts, int* __restrict__ partial, int n){
    __shared__ int sm[256];
    int chunk = (n + 255) >> 8;
    int start = blockIdx.x * chunk;
    int end = min(start + chunk, n);
    int s = 0;
    for(int i = start + threadIdx.x; i < end; i += 256) s += (counts[i] + 7) & ~7;
    sm[threadIdx.x] = s;
    __syncthreads();
    for(int off = 128; off > 0; off >>= 1){
        if(threadIdx.x < off) sm[threadIdx.x] += sm[threadIdx.x + off];
        __syncthreads();
    }
    if(threadIdx.x == 0) partial[blockIdx.x] = sm[0];
}

__global__ void k_scan256(const int* __restrict__ partial, int* __restrict__ pscan){
    __shared__ int sm[256];
    int t = threadIdx.x;
    sm[t] = partial[t];
    __syncthreads();
    for(int off = 1; off < 256; off <<= 1){
        int v = (t >= off) ? sm[t - off] : 0;
        __syncthreads();
        sm[t] += v;
        __syncthreads();
    }
    pscan[t] = (t == 0) ? 0 : sm[t - 1];
}

// finalize padded row_start / cursor / dinv (dinv from TRUE count)
__global__ void k_scan_final(const int* __restrict__ counts, const int* __restrict__ pscan,
                             int n, int* __restrict__ row_start, int* __restrict__ cursor,
                             float* __restrict__ dinv){
    __shared__ int sm[512];
    int chunk = (n + 255) >> 8;
    int b = blockIdx.x, t = threadIdx.x;
    int idx = b * chunk + t;
    int c = (t < chunk && idx < n) ? counts[idx] : 0;
    int cp = (c + 7) & ~7;
    sm[t] = cp;
    __syncthreads();
    for(int off = 1; off < 512; off <<= 1){
        int v = (t >= off) ? sm[t - off] : 0;
        __syncthreads();
        sm[t] += v;
        __syncthreads();
    }
    if(t < chunk && idx < n){
        int rs = pscan[b] + sm[t] - cp;   // exclusive, padded
        row_start[idx] = rs;
        cursor[idx] = rs;
        dinv[idx] = rsqrtf((float)(c + 1));   // +1 self loop
        if(idx == n - 1) row_start[n] = rs + cp;
    }
}

// fill padding gap [cursor_final, row_start[i+1]) with dummy index n
__global__ void k_pad(const int* __restrict__ cursor, const int* __restrict__ row_start,
                      int* __restrict__ esrc, int n){
    int i = blockIdx.x * 256 + threadIdx.x;
    if(i >= n) return;
    int p = cursor[i], p1 = row_start[i + 1];
    for(; p < p1; ++p) esrc[p] = n;
}

// ---------------- W1 split/transpose into MFMA-fragment order ----------------
__global__ void k_wsplit(const float* __restrict__ W, unsigned short* __restrict__ whi,
                         unsigned short* __restrict__ wlo){
    int t = blockIdx.x * 256 + threadIdx.x;      // 4096 threads = (cf,kk,lane)
    int lane = t & 63;
    int kk = (t >> 6) & 15;
    int cf = t >> 10;
    int col = cf * 32 + (lane & 31);
    int kbase = kk * 16 + (lane >> 5) * 8;
    #pragma unroll
    for(int i = 0; i < 8; ++i){
        float f = W[(size_t)(kbase + i) * HDIM + col];
        unsigned u = __float_as_uint(f);
        unsigned short hs = (unsigned short)(u >> 16);            // truncate split
        float lf = f - __uint_as_float(u & 0xffff0000u);
        unsigned short ls = (unsigned short)(__float_as_uint(lf) >> 16);
        whi[(size_t)t * 8 + i] = hs;
        wlo[(size_t)t * 8 + i] = ls;
    }
}

// ---------------- GEMM1 (MFMA split-bf16): h1b = bf16(dinv .* (x @ W1)) ----------------
__device__ inline void split8(const float4 v0, const float4 v1, bf16x8& hi, bf16x8& lo){
    const float f[8] = {v0.x, v0.y, v0.z, v0.w, v1.x, v1.y, v1.z, v1.w};
    #pragma unroll
    for(int i = 0; i < 8; ++i){
        unsigned u = __float_as_uint(f[i]);
        hi[i] = (short)(u >> 16);
        float lf = f[i] - __uint_as_float(u & 0xffff0000u);
        lo[i] = (short)(__float_as_uint(lf) >> 16);
    }
}

__global__ __launch_bounds__(256, 3) void k_gemm1(const float* __restrict__ x,
        const bf16x8* __restrict__ whi, const bf16x8* __restrict__ wlo,
        const float* __restrict__ dinv, unsigned short* __restrict__ hb, int n){
    int wid = blockIdx.x * 4 + (threadIdx.x >> 6);
    if(wid >= (n >> 5)) return;              // 3125 waves exactly (100000 = 32*3125)
    int lane = threadIdx.x & 63;
    int r  = lane & 31;
    int hk = lane >> 5;
    int row0 = wid * 32;

    f32x16 acc[4];
    #pragma unroll
    for(int cf = 0; cf < 4; ++cf)
        #pragma unroll
        for(int i = 0; i < 16; ++i) acc[cf][i] = 0.f;

    const float* ap = x + (size_t)(row0 + r) * INDIM + hk * 8;

    for(int kk = 0; kk < 16; ++kk){          // K = 256, BK = 16
        int ko = kk * 16;
        float4 a0 = *(const float4*)(ap + ko);
        float4 a1 = *(const float4*)(ap + ko + 4);
        bf16x8 bh[4], bl[4];
        #pragma unroll
        for(int cf = 0; cf < 4; ++cf){
            bh[cf] = whi[(cf * 16 + kk) * 64 + lane];
            bl[cf] = wlo[(cf * 16 + kk) * 64 + lane];
        }
        bf16x8 ah, al;
        split8(a0, a1, ah, al);
        #pragma unroll
        for(int cf = 0; cf < 4; ++cf){
            acc[cf] = __builtin_amdgcn_mfma_f32_32x32x16_bf16(ah, bh[cf], acc[cf], 0, 0, 0);
            acc[cf] = __builtin_amdgcn_mfma_f32_32x32x16_bf16(ah, bl[cf], acc[cf], 0, 0, 0);
            acc[cf] = __builtin_amdgcn_mfma_f32_32x32x16_bf16(al, bh[cf], acc[cf], 0, 0, 0);
        }
    }

    #pragma unroll
    for(int reg = 0; reg < 16; ++reg){
        int row = row0 + (reg & 3) + 8 * (reg >> 2) + 4 * hk;
        float di = dinv[row];
        unsigned short* hp = hb + (size_t)row * HDIM + r;
        #pragma unroll
        for(int cf = 0; cf < 4; ++cf)
            hp[cf * 32] = f2bf(acc[cf][reg] * di);
    }
}

// ---------------- GEMM2: h2b = bf16(dinv .* (a @ W2)), [N,128]@[128,40] ----------------
__global__ __launch_bounds__(256) void k_gemm2(const float* __restrict__ a, const float* __restrict__ W,
                                               const float* __restrict__ dinv,
                                               unsigned* __restrict__ hb2, int n){
    __shared__ float xs[64][132];
    __shared__ float ws[HDIM][ODIM];
    int tid = threadIdx.x;
    int row0 = blockIdx.x * 64;
    #pragma unroll
    for(int jj = 0; jj < 8; ++jj){
        int f = tid + 256 * jj;       // float4 index, 2048 total
        int r = f >> 5;
        int c4 = (f & 31) << 2;
        float4 v = make_float4(0.f, 0.f, 0.f, 0.f);
        int grow = row0 + r;
        if(grow < n) v = *(const float4*)&a[(size_t)grow * HDIM + c4];
        *(float4*)&xs[r][c4] = v;
    }
    #pragma unroll
    for(int jj = 0; jj < 5; ++jj){
        int f = tid + 256 * jj;       // 1280 float4 exact
        int r = f / 10;
        int c4 = (f % 10) << 2;
        *(float4*)&ws[r][c4] = *(const float4*)&W[(size_t)r * ODIM + c4];
    }
    __syncthreads();
    int q = tid & 3, r = tid >> 2;
    float acc[10];
    #pragma unroll
    for(int j = 0; j < 10; ++j) acc[j] = 0.f;
    #pragma unroll 4
    for(int k = 0; k < HDIM; ++k){
        float xv = xs[r][k];
        #pragma unroll
        for(int j = 0; j < 5; ++j){
            float2 w = *(const float2*)&ws[k][2 * q + 8 * j];
            acc[2*j+0] += xv * w.x;
            acc[2*j+1] += xv * w.y;
        }
    }
    int grow = row0 + r;
    if(grow < n){
        float dv = dinv[grow];
        #pragma unroll
        for(int j = 0; j < 5; ++j){
            unsigned u = (unsigned)f2bf(acc[2*j] * dv) | ((unsigned)f2bf(acc[2*j+1] * dv) << 16);
            hb2[(size_t)grow * 20 + q + 4 * j] = u;   // ushort cols 2q+8j, 2q+8j+1
        }
    }
}

// ---------------- Aggregation (bf16 message gather over padded CSR) ----------------
// agg1: 2 nodes/wave, 32 lanes/node, uint2 (4 bf16 feats) per lane -> 256B/row.
#define ACC4(m) { acc.x += __uint_as_float((m).x << 16); acc.y += __uint_as_float((m).x & 0xffff0000u); \
                  acc.z += __uint_as_float((m).y << 16); acc.w += __uint_as_float((m).y & 0xffff0000u); }

__global__ __launch_bounds__(256) void k_agg1(const uint2* __restrict__ hb, const int* __restrict__ row_start,
                                              const int* __restrict__ esrc, const float* __restrict__ dinv,
                                              const float4* __restrict__ bias4, float4* __restrict__ out4, int n){
    int wav = (blockIdx.x * 256 + threadIdx.x) >> 6;
    int lane = threadIdx.x & 63;
    int half = lane >> 5;
    int node = wav * 2 + half;
    if(node >= n) return;
    int r32 = lane & 31;                     // 4-feat group 0..31 (128 feats)

    float4 acc = make_float4(0.f, 0.f, 0.f, 0.f);
    { uint2 sv = hb[(size_t)node * 32 + r32]; ACC4(sv); }   // self loop
    int e = row_start[node], e1 = row_start[node + 1];

    for(; e + 16 <= e1; e += 16){
        int4 sa = *(const int4*)&esrc[e];
        int4 sb = *(const int4*)&esrc[e + 4];
        int4 sc = *(const int4*)&esrc[e + 8];
        int4 sd = *(const int4*)&esrc[e + 12];
        uint2 m0  = hb[(size_t)sa.x * 32 + r32];
        uint2 m1  = hb[(size_t)sa.y * 32 + r32];
        uint2 m2  = hb[(size_t)sa.z * 32 + r32];
        uint2 m3  = hb[(size_t)sa.w * 32 + r32];
        uint2 m4  = hb[(size_t)sb.x * 32 + r32];
        uint2 m5  = hb[(size_t)sb.y * 32 + r32];
        uint2 m6  = hb[(size_t)sb.z * 32 + r32];
        uint2 m7  = hb[(size_t)sb.w * 32 + r32];
        uint2 m8  = hb[(size_t)sc.x * 32 + r32];
        uint2 m9  = hb[(size_t)sc.y * 32 + r32];
        uint2 m10 = hb[(size_t)sc.z * 32 + r32];
        uint2 m11 = hb[(size_t)sc.w * 32 + r32];
        uint2 m12 = hb[(size_t)sd.x * 32 + r32];
        uint2 m13 = hb[(size_t)sd.y * 32 + r32];
        uint2 m14 = hb[(size_t)sd.z * 32 + r32];
        uint2 m15 = hb[(size_t)sd.w * 32 + r32];
        ACC4(m0); ACC4(m1); ACC4(m2); ACC4(m3);
        ACC4(m4); ACC4(m5); ACC4(m6); ACC4(m7);
        ACC4(m8); ACC4(m9); ACC4(m10); ACC4(m11);
        ACC4(m12); ACC4(m13); ACC4(m14); ACC4(m15);
    }
    if(e < e1){                               // exactly 8 remain (rows are %8)
        int4 sa = *(const int4*)&esrc[e];
        int4 sb = *(const int4*)&esrc[e + 4];
        uint2 m0 = hb[(size_t)sa.x * 32 + r32];
        uint2 m1 = hb[(size_t)sa.y * 32 + r32];
        uint2 m2 = hb[(size_t)sa.z * 32 + r32];
        uint2 m3 = hb[(size_t)sa.w * 32 + r32];
        uint2 m4 = hb[(size_t)sb.x * 32 + r32];
        uint2 m5 = hb[(size_t)sb.y * 32 + r32];
        uint2 m6 = hb[(size_t)sb.z * 32 + r32];
        uint2 m7 = hb[(size_t)sb.w * 32 + r32];
        ACC4(m0); ACC4(m1); ACC4(m2); ACC4(m3);
        ACC4(m4); ACC4(m5); ACC4(m6); ACC4(m7);
    }

    float di = dinv[node];
    float4 b = bias4[r32];
    float4 o;
    o.x = fmaxf(fmaf(acc.x, di, b.x), 0.f);
    o.y = fmaxf(fmaf(acc.y, di, b.y), 0.f);
    o.z = fmaxf(fmaf(acc.z, di, b.z), 0.f);
    o.w = fmaxf(fmaf(acc.w, di, b.w), 0.f);
    out4[(size_t)node * 32 + r32] = o;
}

// agg2: dim 40 bf16, one wave/node (lanes 0..39), padded rows, int4 idx, 8-deep
__global__ __launch_bounds__(256) void k_agg2(const unsigned short* __restrict__ hb,
                                              const int* __restrict__ row_start,
                                              const int* __restrict__ esrc, const float* __restrict__ dinv,
                                              const float* __restrict__ bias, float* __restrict__ out, int n){
    int wid = (blockIdx.x * 256 + threadIdx.x) >> 6;
    int lane = threadIdx.x & 63;
    if(wid >= n || lane >= ODIM) return;
    float a = __uint_as_float((unsigned)hb[(size_t)wid * ODIM + lane] << 16);   // self loop
    int e = row_start[wid], e1 = row_start[wid + 1];
    for(; e < e1; e += 8){
        int4 sa = *(const int4*)&esrc[e];
        int4 sb = *(const int4*)&esrc[e + 4];
        float m0 = __uint_as_float((unsigned)hb[(size_t)sa.x * ODIM + lane] << 16);
        float m1 = __uint_as_float((unsigned)hb[(size_t)sa.y * ODIM + lane] << 16);
        float m2 = __uint_as_float((unsigned)hb[(size_t)sa.z * ODIM + lane] << 16);
        float m3 = __uint_as_float((unsigned)hb[(size_t)sa.w * ODIM + lane] << 16);
        float m4 = __uint_as_float((unsigned)hb[(size_t)sb.x * ODIM + lane] << 16);
        float m5 = __uint_as_float((unsigned)hb[(size_t)sb.y * ODIM + lane] << 16);
        float m6 = __uint_as_float((unsigned)hb[(size_t)sb.z * ODIM + lane] << 16);
        float m7 = __uint_as_float((unsigned)hb[(size_t)sb.w * ODIM + lane] << 16);
        a += ((m0 + m1) + (m2 + m3)) + ((m4 + m5) + (m6 + m7));
    }
    out[(size_t)wid * ODIM + lane] = fmaf(a, dinv[wid], bias[lane]);
}

extern "C" void kernel_launch(void* const* d_in, const int* in_sizes, int n_in,
                              void* d_out, int out_size, void* d_ws, size_t ws_size,
                              hipStream_t stream){
    const float* x  = (const float*)d_in[0];
    const int*   ei = (const int*)d_in[1];   // [2][E] int32
    const float* W1 = (const float*)d_in[2];
    const float* b1 = (const float*)d_in[3];
    const float* W2 = (const float*)d_in[4];
    const float* b2 = (const float*)d_in[5];
    float* out = (float*)d_out;

    const int n = NODES;
    const int E = in_sizes[1] / 2;
    const int* esrc_in = ei;
    const int* edst_in = ei + E;

    char* w = (char*)d_ws;
    int*   counts    = (int*)(w);                        // 400 KB
    int*   row_start = (int*)(w + (1u << 19));           // 400 KB (+1)
    int*   cursor    = (int*)(w + (2u << 19));           // 400 KB
    int*   partial   = (int*)(w + (3u << 19));           // 1 KB
    int*   pscan     = (int*)(w + (3u << 19) + 4096);    // 1 KB
    float* dinv      = (float*)(w + (4u << 19));         // 400 KB
    unsigned short* whi = (unsigned short*)(w + (6u << 19));   // 64 KB  W1 frag hi
    unsigned short* wlo = (unsigned short*)(w + (7u << 19));   // 64 KB  W1 frag lo
    int*   esrc      = (int*)(w + (4u << 20));           // padded: <=9.6 MB (4..13.6 MB)
    unsigned short* h1b = (unsigned short*)(w + (16u << 20));  // [N+1][128] bf16 = 25.6 MB
    float* h1r       = (float*)(w + (48u << 20));        // [N][128] f32 = 51.2 MB
    unsigned short* h2b = h1b;                            // reuse (h1b dead after agg1), [N+1][40] bf16

    hipMemsetAsync(counts, 0, n * sizeof(int), stream);
    k_hist<<<2048, 256, 0, stream>>>(edst_in, E, counts);
    k_psum<<<256, 256, 0, stream>>>(counts, partial, n);
    k_scan256<<<1, 256, 0, stream>>>(partial, pscan);
    k_scan_final<<<256, 512, 0, stream>>>(counts, pscan, n, row_start, cursor, dinv);
    k_fill<<<2048, 256, 0, stream>>>(esrc_in, edst_in, E, cursor, esrc);
    k_pad<<<(n + 255) / 256, 256, 0, stream>>>(cursor, row_start, esrc, n);
    k_wsplit<<<16, 256, 0, stream>>>(W1, whi, wlo);

    k_gemm1<<<(NODES / 32 + 3) / 4, 256, 0, stream>>>(x, (const bf16x8*)whi, (const bf16x8*)wlo,
                                                      dinv, h1b, n);
    // dummy zero row for agg1 gathers (index n)
    hipMemsetAsync(h1b + (size_t)n * HDIM, 0, HDIM * sizeof(unsigned short), stream);
    k_agg1<<<(n / 2 + 3) / 4, 256, 0, stream>>>((const uint2*)h1b, row_start, esrc, dinv,
                                                (const float4*)b1, (float4*)h1r, n);
    k_gemm2<<<(n + 63) / 64, 256, 0, stream>>>(h1r, W2, dinv, (unsigned*)h2b, n);
    // dummy zero row for agg2 gathers
    hipMemsetAsync(h2b + (size_t)n * ODIM, 0, ODIM * sizeof(unsigned short), stream);
    k_agg2<<<(n * 64 + 255) / 256, 256, 0, stream>>>(h2b, row_start, esrc, dinv, b2, out, n);
}

// Round 12
// 490.098 us; speedup vs baseline: 1.1506x; 1.0114x over previous
//
#include <hip/hip_runtime.h>

#define NODES 100000
#define INDIM 256
#define HDIM 128
#define ODIM 40
#define NPX 12500   // nodes per XCD range (100000/8)

typedef short bf16x8 __attribute__((ext_vector_type(8)));   // 8 bf16 (4 VGPR)
typedef float f32x16 __attribute__((ext_vector_type(16)));  // MFMA 32x32 accumulator

__device__ inline unsigned short f2bf(float f){   // RNE float->bf16
    unsigned u = __float_as_uint(f);
    return (unsigned short)((u + 0x7fffu + ((u >> 16) & 1u)) >> 16);
}

// ---------------- CSR build (XCD-range partitioned, rows padded to %8) ----------------

__global__ __launch_bounds__(256) void k_hist(const int* __restrict__ dst, int E,
                                              int* __restrict__ counts){
    int xcd = blockIdx.x & 7;
    int g   = blockIdx.x >> 3;            // 0..255
    int lo = xcd * NPX, hi = lo + NPX;
    for(int e = g * 256 + threadIdx.x; e < E; e += 65536){
        int d = dst[e];
        if(d >= lo && d < hi) atomicAdd(&counts[d], 1);
    }
}

__global__ __launch_bounds__(256) void k_fill(const int* __restrict__ src, const int* __restrict__ dst,
                                              int E, int* __restrict__ cursor, int* __restrict__ esrc){
    int xcd = blockIdx.x & 7;
    int g   = blockIdx.x >> 3;
    int lo = xcd * NPX, hi = lo + NPX;
    for(int e = g * 256 + threadIdx.x; e < E; e += 65536){
        int d = dst[e];
        if(d >= lo && d < hi){
            int p = atomicAdd(&cursor[d], 1);
            esrc[p] = src[e];
        }
    }
}

// per-chunk partial sums of PADDED counts
__global__ void k_psum(const int* __restrict__ counts, int* __restrict__ partial, int n){
    __shared__ int sm[256];
    int chunk = (n + 255) >> 8;
    int start = blockIdx.x * chunk;
    int end = min(start + chunk, n);
    int s = 0;
    for(int i = start + threadIdx.x; i < end; i += 256) s += (counts[i] + 7) & ~7;
    sm[threadIdx.x] = s;
    __syncthreads();
    for(int off = 128; off > 0; off >>= 1){
        if(threadIdx.x < off) sm[threadIdx.x] += sm[threadIdx.x + off];
        __syncthreads();
    }
    if(threadIdx.x == 0) partial[blockIdx.x] = sm[0];
}

__global__ void k_scan256(const int* __restrict__ partial, int* __restrict__ pscan){
    __shared__ int sm[256];
    int t = threadIdx.x;
    sm[t] = partial[t];
    __syncthreads();
    for(int off = 1; off < 256; off <<= 1){
        int v = (t >= off) ? sm[t - off] : 0;
        __syncthreads();
        sm[t] += v;
        __syncthreads();
    }
    pscan[t] = (t == 0) ? 0 : sm[t - 1];
}

// finalize padded row_start / cursor / dinv (dinv from TRUE count)
__global__ void k_scan_final(const int* __restrict__ counts, const int* __restrict__ pscan,
                             int n, int* __restrict__ row_start, int* __restrict__ cursor,
                             float* __restrict__ dinv){
    __shared__ int sm[512];
    int chunk = (n + 255) >> 8;
    int b = blockIdx.x, t = threadIdx.x;
    int idx = b * chunk + t;
    int c = (t < chunk && idx < n) ? counts[idx] : 0;
    int cp = (c + 7) & ~7;
    sm[t] = cp;
    __syncthreads();
    for(int off = 1; off < 512; off <<= 1){
        int v = (t >= off) ? sm[t - off] : 0;
        __syncthreads();
        sm[t] += v;
        __syncthreads();
    }
    if(t < chunk && idx < n){
        int rs = pscan[b] + sm[t] - cp;   // exclusive, padded
        row_start[idx] = rs;
        cursor[idx] = rs;
        dinv[idx] = rsqrtf((float)(c + 1));   // +1 self loop
        if(idx == n - 1) row_start[n] = rs + cp;
    }
}

// fill padding gap [cursor_final, row_start[i+1]) with dummy index n
__global__ void k_pad(const int* __restrict__ cursor, const int* __restrict__ row_start,
                      int* __restrict__ esrc, int n){
    int i = blockIdx.x * 256 + threadIdx.x;
    if(i >= n) return;
    int p = cursor[i], p1 = row_start[i + 1];
    for(; p < p1; ++p) esrc[p] = n;
}

// ---------------- W1 split/transpose into MFMA-fragment order ----------------
__global__ void k_wsplit(const float* __restrict__ W, unsigned short* __restrict__ whi,
                         unsigned short* __restrict__ wlo){
    int t = blockIdx.x * 256 + threadIdx.x;      // 4096 threads = (cf,kk,lane)
    int lane = t & 63;
    int kk = (t >> 6) & 15;
    int cf = t >> 10;
    int col = cf * 32 + (lane & 31);
    int kbase = kk * 16 + (lane >> 5) * 8;
    #pragma unroll
    for(int i = 0; i < 8; ++i){
        float f = W[(size_t)(kbase + i) * HDIM + col];
        unsigned u = __float_as_uint(f);
        unsigned short hs = (unsigned short)(u >> 16);            // truncate split
        float lf = f - __uint_as_float(u & 0xffff0000u);
        unsigned short ls = (unsigned short)(__float_as_uint(lf) >> 16);
        whi[(size_t)t * 8 + i] = hs;
        wlo[(size_t)t * 8 + i] = ls;
    }
}

// ---------------- GEMM1 (MFMA split-bf16, SW-pipelined): h1b = bf16(dinv .* (x @ W1)) ----------------
__device__ inline void split8(const float4 v0, const float4 v1, bf16x8& hi, bf16x8& lo){
    const float f[8] = {v0.x, v0.y, v0.z, v0.w, v1.x, v1.y, v1.z, v1.w};
    #pragma unroll
    for(int i = 0; i < 8; ++i){
        unsigned u = __float_as_uint(f[i]);
        hi[i] = (short)(u >> 16);
        float lf = f[i] - __uint_as_float(u & 0xffff0000u);
        lo[i] = (short)(__float_as_uint(lf) >> 16);
    }
}

// Per-step: issue B(kk) first, split A(kk) (waits only 2 oldest), issue A(kk+4)
// prefetch, then 12 MFMA (vmcnt wait drains B(kk)+older A's, keeps A(kk+4) in
// flight). Named rotating prefetch regs -> static indices -> registers (rule #20).
#define MFMA_BF16 __builtin_amdgcn_mfma_f32_32x32x16_bf16
#define GSTEP(kk, PA, PB) { \
    bf16x8 bh0 = whi[(0 * 16 + (kk)) * 64 + lane]; \
    bf16x8 bh1 = whi[(1 * 16 + (kk)) * 64 + lane]; \
    bf16x8 bh2 = whi[(2 * 16 + (kk)) * 64 + lane]; \
    bf16x8 bh3 = whi[(3 * 16 + (kk)) * 64 + lane]; \
    bf16x8 bl0 = wlo[(0 * 16 + (kk)) * 64 + lane]; \
    bf16x8 bl1 = wlo[(1 * 16 + (kk)) * 64 + lane]; \
    bf16x8 bl2 = wlo[(2 * 16 + (kk)) * 64 + lane]; \
    bf16x8 bl3 = wlo[(3 * 16 + (kk)) * 64 + lane]; \
    bf16x8 ah, al; \
    split8(PA, PB, ah, al); \
    if((kk) < 12){ \
        PA = *(const float4*)(ap + ((kk) + 4) * 16); \
        PB = *(const float4*)(ap + ((kk) + 4) * 16 + 4); \
    } \
    acc[0] = MFMA_BF16(ah, bh0, acc[0], 0, 0, 0); \
    acc[1] = MFMA_BF16(ah, bh1, acc[1], 0, 0, 0); \
    acc[2] = MFMA_BF16(ah, bh2, acc[2], 0, 0, 0); \
    acc[3] = MFMA_BF16(ah, bh3, acc[3], 0, 0, 0); \
    acc[0] = MFMA_BF16(al, bh0, acc[0], 0, 0, 0); \
    acc[1] = MFMA_BF16(al, bh1, acc[1], 0, 0, 0); \
    acc[2] = MFMA_BF16(al, bh2, acc[2], 0, 0, 0); \
    acc[3] = MFMA_BF16(al, bh3, acc[3], 0, 0, 0); \
    acc[0] = MFMA_BF16(ah, bl0, acc[0], 0, 0, 0); \
    acc[1] = MFMA_BF16(ah, bl1, acc[1], 0, 0, 0); \
    acc[2] = MFMA_BF16(ah, bl2, acc[2], 0, 0, 0); \
    acc[3] = MFMA_BF16(ah, bl3, acc[3], 0, 0, 0); \
}

__global__ __launch_bounds__(256, 3) void k_gemm1(const float* __restrict__ x,
        const bf16x8* __restrict__ whi, const bf16x8* __restrict__ wlo,
        const float* __restrict__ dinv, unsigned short* __restrict__ hb, int n){
    int wid = blockIdx.x * 4 + (threadIdx.x >> 6);
    if(wid >= (n >> 5)) return;              // 3125 waves exactly (100000 = 32*3125)
    int lane = threadIdx.x & 63;
    int r  = lane & 31;
    int hk = lane >> 5;
    int row0 = wid * 32;

    f32x16 acc[4];
    #pragma unroll
    for(int cf = 0; cf < 4; ++cf)
        #pragma unroll
        for(int i = 0; i < 16; ++i) acc[cf][i] = 0.f;

    const float* ap = x + (size_t)(row0 + r) * INDIM + hk * 8;

    // prime A prefetch pipeline (depth 4)
    float4 a0 = *(const float4*)(ap +  0), b0 = *(const float4*)(ap +  4);
    float4 a1 = *(const float4*)(ap + 16), b1 = *(const float4*)(ap + 20);
    float4 a2 = *(const float4*)(ap + 32), b2 = *(const float4*)(ap + 36);
    float4 a3 = *(const float4*)(ap + 48), b3 = *(const float4*)(ap + 52);

    GSTEP( 0, a0, b0)  GSTEP( 1, a1, b1)  GSTEP( 2, a2, b2)  GSTEP( 3, a3, b3)
    GSTEP( 4, a0, b0)  GSTEP( 5, a1, b1)  GSTEP( 6, a2, b2)  GSTEP( 7, a3, b3)
    GSTEP( 8, a0, b0)  GSTEP( 9, a1, b1)  GSTEP(10, a2, b2)  GSTEP(11, a3, b3)
    GSTEP(12, a0, b0)  GSTEP(13, a1, b1)  GSTEP(14, a2, b2)  GSTEP(15, a3, b3)

    #pragma unroll
    for(int reg = 0; reg < 16; ++reg){
        int row = row0 + (reg & 3) + 8 * (reg >> 2) + 4 * hk;
        float di = dinv[row];
        unsigned short* hp = hb + (size_t)row * HDIM + r;
        #pragma unroll
        for(int cf = 0; cf < 4; ++cf)
            hp[cf * 32] = f2bf(acc[cf][reg] * di);
    }
}

// ---------------- GEMM2: h2b = bf16(dinv .* (a @ W2)), [N,128]@[128,40] ----------------
__global__ __launch_bounds__(256) void k_gemm2(const float* __restrict__ a, const float* __restrict__ W,
                                               const float* __restrict__ dinv,
                                               unsigned* __restrict__ hb2, int n){
    __shared__ float xs[64][132];
    __shared__ float ws[HDIM][ODIM];
    int tid = threadIdx.x;
    int row0 = blockIdx.x * 64;
    #pragma unroll
    for(int jj = 0; jj < 8; ++jj){
        int f = tid + 256 * jj;       // float4 index, 2048 total
        int r = f >> 5;
        int c4 = (f & 31) << 2;
        float4 v = make_float4(0.f, 0.f, 0.f, 0.f);
        int grow = row0 + r;
        if(grow < n) v = *(const float4*)&a[(size_t)grow * HDIM + c4];
        *(float4*)&xs[r][c4] = v;
    }
    #pragma unroll
    for(int jj = 0; jj < 5; ++jj){
        int f = tid + 256 * jj;       // 1280 float4 exact
        int r = f / 10;
        int c4 = (f % 10) << 2;
        *(float4*)&ws[r][c4] = *(const float4*)&W[(size_t)r * ODIM + c4];
    }
    __syncthreads();
    int q = tid & 3, r = tid >> 2;
    float acc[10];
    #pragma unroll
    for(int j = 0; j < 10; ++j) acc[j] = 0.f;
    #pragma unroll 4
    for(int k = 0; k < HDIM; ++k){
        float xv = xs[r][k];
        #pragma unroll
        for(int j = 0; j < 5; ++j){
            float2 w = *(const float2*)&ws[k][2 * q + 8 * j];
            acc[2*j+0] += xv * w.x;
            acc[2*j+1] += xv * w.y;
        }
    }
    int grow = row0 + r;
    if(grow < n){
        float dv = dinv[grow];
        #pragma unroll
        for(int j = 0; j < 5; ++j){
            unsigned u = (unsigned)f2bf(acc[2*j] * dv) | ((unsigned)f2bf(acc[2*j+1] * dv) << 16);
            hb2[(size_t)grow * 20 + q + 4 * j] = u;   // ushort cols 2q+8j, 2q+8j+1
        }
    }
}

// ---------------- Aggregation (bf16 message gather over padded CSR) ----------------
// agg1: 2 nodes/wave, 32 lanes/node, uint2 (4 bf16 feats) per lane -> 256B/row.
#define ACC4(m) { acc.x += __uint_as_float((m).x << 16); acc.y += __uint_as_float((m).x & 0xffff0000u); \
                  acc.z += __uint_as_float((m).y << 16); acc.w += __uint_as_float((m).y & 0xffff0000u); }

__global__ __launch_bounds__(256) void k_agg1(const uint2* __restrict__ hb, const int* __restrict__ row_start,
                                              const int* __restrict__ esrc, const float* __restrict__ dinv,
                                              const float4* __restrict__ bias4, float4* __restrict__ out4, int n){
    int wav = (blockIdx.x * 256 + threadIdx.x) >> 6;
    int lane = threadIdx.x & 63;
    int half = lane >> 5;
    int node = wav * 2 + half;
    if(node >= n) return;
    int r32 = lane & 31;                     // 4-feat group 0..31 (128 feats)

    float4 acc = make_float4(0.f, 0.f, 0.f, 0.f);
    { uint2 sv = hb[(size_t)node * 32 + r32]; ACC4(sv); }   // self loop
    int e = row_start[node], e1 = row_start[node + 1];

    for(; e + 16 <= e1; e += 16){
        int4 sa = *(const int4*)&esrc[e];
        int4 sb = *(const int4*)&esrc[e + 4];
        int4 sc = *(const int4*)&esrc[e + 8];
        int4 sd = *(const int4*)&esrc[e + 12];
        uint2 m0  = hb[(size_t)sa.x * 32 + r32];
        uint2 m1  = hb[(size_t)sa.y * 32 + r32];
        uint2 m2  = hb[(size_t)sa.z * 32 + r32];
        uint2 m3  = hb[(size_t)sa.w * 32 + r32];
        uint2 m4  = hb[(size_t)sb.x * 32 + r32];
        uint2 m5  = hb[(size_t)sb.y * 32 + r32];
        uint2 m6  = hb[(size_t)sb.z * 32 + r32];
        uint2 m7  = hb[(size_t)sb.w * 32 + r32];
        uint2 m8  = hb[(size_t)sc.x * 32 + r32];
        uint2 m9  = hb[(size_t)sc.y * 32 + r32];
        uint2 m10 = hb[(size_t)sc.z * 32 + r32];
        uint2 m11 = hb[(size_t)sc.w * 32 + r32];
        uint2 m12 = hb[(size_t)sd.x * 32 + r32];
        uint2 m13 = hb[(size_t)sd.y * 32 + r32];
        uint2 m14 = hb[(size_t)sd.z * 32 + r32];
        uint2 m15 = hb[(size_t)sd.w * 32 + r32];
        ACC4(m0); ACC4(m1); ACC4(m2); ACC4(m3);
        ACC4(m4); ACC4(m5); ACC4(m6); ACC4(m7);
        ACC4(m8); ACC4(m9); ACC4(m10); ACC4(m11);
        ACC4(m12); ACC4(m13); ACC4(m14); ACC4(m15);
    }
    if(e < e1){                               // exactly 8 remain (rows are %8)
        int4 sa = *(const int4*)&esrc[e];
        int4 sb = *(const int4*)&esrc[e + 4];
        uint2 m0 = hb[(size_t)sa.x * 32 + r32];
        uint2 m1 = hb[(size_t)sa.y * 32 + r32];
        uint2 m2 = hb[(size_t)sa.z * 32 + r32];
        uint2 m3 = hb[(size_t)sa.w * 32 + r32];
        uint2 m4 = hb[(size_t)sb.x * 32 + r32];
        uint2 m5 = hb[(size_t)sb.y * 32 + r32];
        uint2 m6 = hb[(size_t)sb.z * 32 + r32];
        uint2 m7 = hb[(size_t)sb.w * 32 + r32];
        ACC4(m0); ACC4(m1); ACC4(m2); ACC4(m3);
        ACC4(m4); ACC4(m5); ACC4(m6); ACC4(m7);
    }

    float di = dinv[node];
    float4 b = bias4[r32];
    float4 o;
    o.x = fmaxf(fmaf(acc.x, di, b.x), 0.f);
    o.y = fmaxf(fmaf(acc.y, di, b.y), 0.f);
    o.z = fmaxf(fmaf(acc.z, di, b.z), 0.f);
    o.w = fmaxf(fmaf(acc.w, di, b.w), 0.f);
    out4[(size_t)node * 32 + r32] = o;
}

// agg2: dim 40 bf16, one wave/node (lanes 0..39), padded rows, int4 idx, 8-deep
__global__ __launch_bounds__(256) void k_agg2(const unsigned short* __restrict__ hb,
                                              const int* __restrict__ row_start,
                                              const int* __restrict__ esrc, const float* __restrict__ dinv,
                                              const float* __restrict__ bias, float* __restrict__ out, int n){
    int wid = (blockIdx.x * 256 + threadIdx.x) >> 6;
    int lane = threadIdx.x & 63;
    if(wid >= n || lane >= ODIM) return;
    float a = __uint_as_float((unsigned)hb[(size_t)wid * ODIM + lane] << 16);   // self loop
    int e = row_start[wid], e1 = row_start[wid + 1];
    for(; e < e1; e += 8){
        int4 sa = *(const int4*)&esrc[e];
        int4 sb = *(const int4*)&esrc[e + 4];
        float m0 = __uint_as_float((unsigned)hb[(size_t)sa.x * ODIM + lane] << 16);
        float m1 = __uint_as_float((unsigned)hb[(size_t)sa.y * ODIM + lane] << 16);
        float m2 = __uint_as_float((unsigned)hb[(size_t)sa.z * ODIM + lane] << 16);
        float m3 = __uint_as_float((unsigned)hb[(size_t)sa.w * ODIM + lane] << 16);
        float m4 = __uint_as_float((unsigned)hb[(size_t)sb.x * ODIM + lane] << 16);
        float m5 = __uint_as_float((unsigned)hb[(size_t)sb.y * ODIM + lane] << 16);
        float m6 = __uint_as_float((unsigned)hb[(size_t)sb.z * ODIM + lane] << 16);
        float m7 = __uint_as_float((unsigned)hb[(size_t)sb.w * ODIM + lane] << 16);
        a += ((m0 + m1) + (m2 + m3)) + ((m4 + m5) + (m6 + m7));
    }
    out[(size_t)wid * ODIM + lane] = fmaf(a, dinv[wid], bias[lane]);
}

extern "C" void kernel_launch(void* const* d_in, const int* in_sizes, int n_in,
                              void* d_out, int out_size, void* d_ws, size_t ws_size,
                              hipStream_t stream){
    const float* x  = (const float*)d_in[0];
    const int*   ei = (const int*)d_in[1];   // [2][E] int32
    const float* W1 = (const float*)d_in[2];
    const float* b1 = (const float*)d_in[3];
    const float* W2 = (const float*)d_in[4];
    const float* b2 = (const float*)d_in[5];
    float* out = (float*)d_out;

    const int n = NODES;
    const int E = in_sizes[1] / 2;
    const int* esrc_in = ei;
    const int* edst_in = ei + E;

    char* w = (char*)d_ws;
    int*   counts    = (int*)(w);                        // 400 KB
    int*   row_start = (int*)(w + (1u << 19));           // 400 KB (+1)
    int*   cursor    = (int*)(w + (2u << 19));           // 400 KB
    int*   partial   = (int*)(w + (3u << 19));           // 1 KB
    int*   pscan     = (int*)(w + (3u << 19) + 4096);    // 1 KB
    float* dinv      = (float*)(w + (4u << 19));         // 400 KB
    unsigned short* whi = (unsigned short*)(w + (6u << 19));   // 64 KB  W1 frag hi
    unsigned short* wlo = (unsigned short*)(w + (7u << 19));   // 64 KB  W1 frag lo
    int*   esrc      = (int*)(w + (4u << 20));           // padded: <=9.6 MB (4..13.6 MB)
    unsigned short* h1b = (unsigned short*)(w + (16u << 20));  // [N+1][128] bf16 = 25.6 MB
    float* h1r       = (float*)(w + (48u << 20));        // [N][128] f32 = 51.2 MB
    unsigned short* h2b = h1b;                            // reuse (h1b dead after agg1), [N+1][40] bf16

    hipMemsetAsync(counts, 0, n * sizeof(int), stream);
    k_hist<<<2048, 256, 0, stream>>>(edst_in, E, counts);
    k_psum<<<256, 256, 0, stream>>>(counts, partial, n);
    k_scan256<<<1, 256, 0, stream>>>(partial, pscan);
    k_scan_final<<<256, 512, 0, stream>>>(counts, pscan, n, row_start, cursor, dinv);
    k_fill<<<2048, 256, 0, stream>>>(esrc_in, edst_in, E, cursor, esrc);
    k_pad<<<(n + 255) / 256, 256, 0, stream>>>(cursor, row_start, esrc, n);
    k_wsplit<<<16, 256, 0, stream>>>(W1, whi, wlo);

    k_gemm1<<<(NODES / 32 + 3) / 4, 256, 0, stream>>>(x, (const bf16x8*)whi, (const bf16x8*)wlo,
                                                      dinv, h1b, n);
    // dummy zero row for agg1 gathers (index n)
    hipMemsetAsync(h1b + (size_t)n * HDIM, 0, HDIM * sizeof(unsigned short), stream);
    k_agg1<<<(n / 2 + 3) / 4, 256, 0, stream>>>((const uint2*)h1b, row_start, esrc, dinv,
                                                (const float4*)b1, (float4*)h1r, n);
    k_gemm2<<<(n + 63) / 64, 256, 0, stream>>>(h1r, W2, dinv, (unsigned*)h2b, n);
    // dummy zero row for agg2 gathers
    hipMemsetAsync(h2b + (size_t)n * ODIM, 0, ODIM * sizeof(unsigned short), stream);
    k_agg2<<<(n * 64 + 255) / 256, 256, 0, stream>>>(h2b, row_start, esrc, dinv, b2, out, n);
}